// Round 3
// baseline (996.915 us; speedup 1.0000x reference)
//
#include <hip/hip_runtime.h>
#include <math.h>

// GCN 2-layer fused: N=100000 nodes, E=4800000 edges.
// Layer1 input is scalar -> aggregate scalar p[n]=x[n]*dinv[n].
// Layer2 message is 2-wide g[n]=dinv[n]*(relu(W1*s+b1)@W2).

#define NNODES 100000
#define NEDGES 4800000

__global__ void count_deg_k(const int* __restrict__ dst, int* __restrict__ degi, int E) {
    int i = blockIdx.x * blockDim.x + threadIdx.x;
    if (i < E) atomicAdd(&degi[dst[i]], 1);
}

__global__ void node1_k(const float* __restrict__ x, const int* __restrict__ degi,
                        float* __restrict__ dinv, float* __restrict__ p, int N) {
    int n = blockIdx.x * blockDim.x + threadIdx.x;
    if (n < N) {
        float d = (float)(degi[n] + 1);   // +1 self-loop
        float di = rsqrtf(d);
        dinv[n] = di;
        p[n] = x[n] * di;
    }
}

__global__ void scatter1_k(const int* __restrict__ src, const int* __restrict__ dst,
                           const float* __restrict__ p, float* __restrict__ acc1, int E) {
    int i = blockIdx.x * blockDim.x + threadIdx.x;
    if (i < E) atomicAdd(&acc1[dst[i]], p[src[i]]);
}

__global__ void node2_k(const float* __restrict__ dinv, const float* __restrict__ p,
                        const float* __restrict__ acc1,
                        const float* __restrict__ W1, const float* __restrict__ b1,
                        const float* __restrict__ W2,
                        float2* __restrict__ g, int N) {
    int n = blockIdx.x * blockDim.x + threadIdx.x;
    if (n < N) {
        float di = dinv[n];
        float s = di * (p[n] + acc1[n]);  // layer1 normalized aggregate (incl self-loop)
        float g0 = 0.f, g1 = 0.f;
        #pragma unroll
        for (int k = 0; k < 16; ++k) {
            float h = fmaxf(fmaf(W1[k], s, b1[k]), 0.f);  // relu(layer1 out)
            g0 = fmaf(h, W2[2 * k + 0], g0);
            g1 = fmaf(h, W2[2 * k + 1], g1);
        }
        g[n] = make_float2(g0 * di, g1 * di);
    }
}

__global__ void scatter2_k(const int* __restrict__ src, const int* __restrict__ dst,
                           const float2* __restrict__ g, float* __restrict__ acc2, int E) {
    int i = blockIdx.x * blockDim.x + threadIdx.x;
    if (i < E) {
        float2 gv = g[src[i]];
        int d = dst[i];
        atomicAdd(&acc2[2 * d + 0], gv.x);
        atomicAdd(&acc2[2 * d + 1], gv.y);
    }
}

__global__ void final_k(const float* __restrict__ dinv, const float2* __restrict__ g,
                        const float2* __restrict__ acc2, const float* __restrict__ b2,
                        float2* __restrict__ out, int N) {
    int n = blockIdx.x * blockDim.x + threadIdx.x;
    if (n < N) {
        float di = dinv[n];
        float2 gv = g[n];
        float2 av = acc2[n];
        float o0 = fmaf(di, gv.x + av.x, b2[0]);
        float o1 = fmaf(di, gv.y + av.y, b2[1]);
        float m = fmaxf(o0, o1);
        float lse = m + logf(expf(o0 - m) + expf(o1 - m));
        out[n] = make_float2(o0 - lse, o1 - lse);
    }
}

extern "C" void kernel_launch(void* const* d_in, const int* in_sizes, int n_in,
                              void* d_out, int out_size, void* d_ws, size_t ws_size,
                              hipStream_t stream) {
    const float* x  = (const float*)d_in[0];   // [N,1]
    const int*   ei = (const int*)d_in[1];     // [2,E] row0=src, row1=dst
    const float* W1 = (const float*)d_in[2];   // [1,16]
    const float* b1 = (const float*)d_in[3];   // [16]
    const float* W2 = (const float*)d_in[4];   // [16,2]
    const float* b2 = (const float*)d_in[5];   // [2]
    float2* out = (float2*)d_out;              // [N,2] f32

    const int N = in_sizes[0];
    const int E = in_sizes[1] / 2;
    const int* src = ei;
    const int* dst = ei + E;

    // workspace layout (bytes):
    // [0, 4N)      degi   (int)
    // [4N, 8N)     acc1   (float)
    // [8N, 16N)    acc2   (float2 as float[2N])
    // [16N, 20N)   dinv   (float)
    // [20N, 24N)   p      (float)
    // [24N, 32N)   g      (float2)
    char* ws = (char*)d_ws;
    int*    degi = (int*)(ws);
    float*  acc1 = (float*)(ws + 4UL * N);
    float*  acc2 = (float*)(ws + 8UL * N);
    float*  dinv = (float*)(ws + 16UL * N);
    float*  p    = (float*)(ws + 20UL * N);
    float2* g    = (float2*)(ws + 24UL * N);

    // zero degi + acc1 + acc2 in one shot (contiguous 16N bytes)
    hipMemsetAsync(ws, 0, 16UL * N, stream);

    const int B = 256;
    const int gE = (E + B - 1) / B;
    const int gN = (N + B - 1) / B;

    count_deg_k<<<gE, B, 0, stream>>>(dst, degi, E);
    node1_k<<<gN, B, 0, stream>>>(x, degi, dinv, p, N);
    scatter1_k<<<gE, B, 0, stream>>>(src, dst, p, acc1, E);
    node2_k<<<gN, B, 0, stream>>>(dinv, p, acc1, W1, b1, W2, g, N);
    scatter2_k<<<gE, B, 0, stream>>>(src, dst, g, acc2, E);
    final_k<<<gN, B, 0, stream>>>(dinv, g, (const float2*)acc2, b2, out, N);
}

// Round 4
// 539.773 us; speedup vs baseline: 1.8469x; 1.8469x over previous
//
#include <hip/hip_runtime.h>
#include <math.h>

// GCN 2-layer, algebraically collapsed:
//   layer1 aggregates the SCALAR p[n]=x[n]*dinv[n]; layer2 aggregates the
//   2-vector g[n]=dinv[n]*(relu(W1*s+b1)@W2).
// Round-3 baseline (997us) was atomic-throughput bound (~20G atomics/s,
// memory-side write-through ~32B/atomic). This version builds a padded CSR
// (one 4.8M int-atomic pass, which also yields degrees) and replaces all
// float-atomic scatters with wave-per-node gathers from L2-resident arrays.

#define CSR_STRIDE 128   // Poisson(48) in-degree; P(deg>128) ~ 1e-20

// ---------------- CSR path ----------------

__global__ void fill_k(const int* __restrict__ src, const int* __restrict__ dst,
                       int* __restrict__ cnt, int* __restrict__ csr, int E) {
    int i = blockIdx.x * blockDim.x + threadIdx.x;
    if (i < E) {
        int d = dst[i];
        int slot = atomicAdd(&cnt[d], 1);
        if (slot < CSR_STRIDE) csr[(size_t)d * CSR_STRIDE + slot] = src[i];
    }
}

__global__ void node1_k(const float* __restrict__ x, const int* __restrict__ cnt,
                        float* __restrict__ dinv, float* __restrict__ p, int N) {
    int n = blockIdx.x * blockDim.x + threadIdx.x;
    if (n < N) {
        float d = (float)(cnt[n] + 1);   // +1 self-loop
        float di = rsqrtf(d);
        dinv[n] = di;
        p[n] = x[n] * di;
    }
}

// wave-per-node: lanes gather p[src] for this node's in-edges, shfl-reduce,
// then compute the fused 16-wide MLP -> g[n] (2-vector, pre-scaled by dinv).
__global__ void gather1_k(const int* __restrict__ cnt, const int* __restrict__ csr,
                          const float* __restrict__ dinv, const float* __restrict__ p,
                          const float* __restrict__ W1, const float* __restrict__ b1,
                          const float* __restrict__ W2,
                          float2* __restrict__ g, int N) {
    int wid  = (blockIdx.x * blockDim.x + threadIdx.x) >> 6;
    int lane = threadIdx.x & 63;
    if (wid >= N) return;
    int deg = cnt[wid];
    if (deg > CSR_STRIDE) deg = CSR_STRIDE;
    const int* row = csr + (size_t)wid * CSR_STRIDE;
    float sum = 0.f;
    for (int j = lane; j < deg; j += 64) sum += p[row[j]];
    #pragma unroll
    for (int off = 32; off; off >>= 1) sum += __shfl_down(sum, off);
    sum = __shfl(sum, 0);
    float di = dinv[wid];
    float s = di * (p[wid] + sum);       // layer1 normalized aggregate
    float g0 = 0.f, g1 = 0.f;
    #pragma unroll
    for (int k = 0; k < 16; ++k) {
        float h = fmaxf(fmaf(W1[k], s, b1[k]), 0.f);
        g0 = fmaf(h, W2[2 * k + 0], g0);
        g1 = fmaf(h, W2[2 * k + 1], g1);
    }
    if (lane == 0) g[wid] = make_float2(g0 * di, g1 * di);
}

// wave-per-node: gather g[src] (float2), reduce, fused bias + log_softmax.
__global__ void gather2_k(const int* __restrict__ cnt, const int* __restrict__ csr,
                          const float* __restrict__ dinv, const float2* __restrict__ g,
                          const float* __restrict__ b2,
                          float2* __restrict__ out, int N) {
    int wid  = (blockIdx.x * blockDim.x + threadIdx.x) >> 6;
    int lane = threadIdx.x & 63;
    if (wid >= N) return;
    int deg = cnt[wid];
    if (deg > CSR_STRIDE) deg = CSR_STRIDE;
    const int* row = csr + (size_t)wid * CSR_STRIDE;
    float s0 = 0.f, s1 = 0.f;
    for (int j = lane; j < deg; j += 64) {
        float2 gv = g[row[j]];
        s0 += gv.x;
        s1 += gv.y;
    }
    #pragma unroll
    for (int off = 32; off; off >>= 1) {
        s0 += __shfl_down(s0, off);
        s1 += __shfl_down(s1, off);
    }
    s0 = __shfl(s0, 0);
    s1 = __shfl(s1, 0);
    if (lane == 0) {
        float di = dinv[wid];
        float2 gv = g[wid];
        float o0 = fmaf(di, gv.x + s0, b2[0]);
        float o1 = fmaf(di, gv.y + s1, b2[1]);
        float m = fmaxf(o0, o1);
        float lse = m + logf(expf(o0 - m) + expf(o1 - m));
        out[wid] = make_float2(o0 - lse, o1 - lse);
    }
}

// ---------------- fallback atomic path (round-3 baseline) ----------------

__global__ void count_deg_k(const int* __restrict__ dst, int* __restrict__ degi, int E) {
    int i = blockIdx.x * blockDim.x + threadIdx.x;
    if (i < E) atomicAdd(&degi[dst[i]], 1);
}

__global__ void scatter1_k(const int* __restrict__ src, const int* __restrict__ dst,
                           const float* __restrict__ p, float* __restrict__ acc1, int E) {
    int i = blockIdx.x * blockDim.x + threadIdx.x;
    if (i < E) atomicAdd(&acc1[dst[i]], p[src[i]]);
}

__global__ void node2_k(const float* __restrict__ dinv, const float* __restrict__ p,
                        const float* __restrict__ acc1,
                        const float* __restrict__ W1, const float* __restrict__ b1,
                        const float* __restrict__ W2,
                        float2* __restrict__ g, int N) {
    int n = blockIdx.x * blockDim.x + threadIdx.x;
    if (n < N) {
        float di = dinv[n];
        float s = di * (p[n] + acc1[n]);
        float g0 = 0.f, g1 = 0.f;
        #pragma unroll
        for (int k = 0; k < 16; ++k) {
            float h = fmaxf(fmaf(W1[k], s, b1[k]), 0.f);
            g0 = fmaf(h, W2[2 * k + 0], g0);
            g1 = fmaf(h, W2[2 * k + 1], g1);
        }
        g[n] = make_float2(g0 * di, g1 * di);
    }
}

__global__ void scatter2_k(const int* __restrict__ src, const int* __restrict__ dst,
                           const float2* __restrict__ g, float* __restrict__ acc2, int E) {
    int i = blockIdx.x * blockDim.x + threadIdx.x;
    if (i < E) {
        float2 gv = g[src[i]];
        int d = dst[i];
        atomicAdd(&acc2[2 * d + 0], gv.x);
        atomicAdd(&acc2[2 * d + 1], gv.y);
    }
}

__global__ void final_k(const float* __restrict__ dinv, const float2* __restrict__ g,
                        const float2* __restrict__ acc2, const float* __restrict__ b2,
                        float2* __restrict__ out, int N) {
    int n = blockIdx.x * blockDim.x + threadIdx.x;
    if (n < N) {
        float di = dinv[n];
        float2 gv = g[n];
        float2 av = acc2[n];
        float o0 = fmaf(di, gv.x + av.x, b2[0]);
        float o1 = fmaf(di, gv.y + av.y, b2[1]);
        float m = fmaxf(o0, o1);
        float lse = m + logf(expf(o0 - m) + expf(o1 - m));
        out[n] = make_float2(o0 - lse, o1 - lse);
    }
}

extern "C" void kernel_launch(void* const* d_in, const int* in_sizes, int n_in,
                              void* d_out, int out_size, void* d_ws, size_t ws_size,
                              hipStream_t stream) {
    const float* x  = (const float*)d_in[0];   // [N,1]
    const int*   ei = (const int*)d_in[1];     // [2,E] row0=src, row1=dst
    const float* W1 = (const float*)d_in[2];   // [1,16]
    const float* b1 = (const float*)d_in[3];   // [16]
    const float* W2 = (const float*)d_in[4];   // [16,2]
    const float* b2 = (const float*)d_in[5];   // [2]
    float2* out = (float2*)d_out;              // [N,2] f32

    const int N = in_sizes[0];
    const int E = in_sizes[1] / 2;
    const int* src = ei;
    const int* dst = ei + E;

    const int B = 256;
    const int gE = (E + B - 1) / B;
    const int gN = (N + B - 1) / B;

    // CSR-path workspace layout (bytes):
    //   [0, 4N)        cnt (int, memset 0)  -> becomes degree after fill
    //   [4N, 8N)       dinv
    //   [8N, 12N)      p
    //   [16N, 24N)     g (float2)
    //   [24N, 24N+512N) csr (int, N*CSR_STRIDE)
    size_t need = 24UL * N + 4UL * N * CSR_STRIDE;
    if (ws_size >= need) {
        char* ws = (char*)d_ws;
        int*    cnt  = (int*)(ws);
        float*  dinv = (float*)(ws + 4UL * N);
        float*  p    = (float*)(ws + 8UL * N);
        float2* g    = (float2*)(ws + 16UL * N);
        int*    csr  = (int*)(ws + 24UL * N);

        hipMemsetAsync(cnt, 0, 4UL * N, stream);
        fill_k<<<gE, B, 0, stream>>>(src, dst, cnt, csr, E);
        node1_k<<<gN, B, 0, stream>>>(x, cnt, dinv, p, N);
        const int gW = (N * 64 + B - 1) / B;   // wave per node
        gather1_k<<<gW, B, 0, stream>>>(cnt, csr, dinv, p, W1, b1, W2, g, N);
        gather2_k<<<gW, B, 0, stream>>>(cnt, csr, dinv, g, b2, out, N);
    } else {
        // fallback: round-3 atomic pipeline
        char* ws = (char*)d_ws;
        int*    degi = (int*)(ws);
        float*  acc1 = (float*)(ws + 4UL * N);
        float*  acc2 = (float*)(ws + 8UL * N);
        float*  dinv = (float*)(ws + 16UL * N);
        float*  p    = (float*)(ws + 20UL * N);
        float2* g    = (float2*)(ws + 24UL * N);

        hipMemsetAsync(ws, 0, 16UL * N, stream);
        count_deg_k<<<gE, B, 0, stream>>>(dst, degi, E);
        node1_k<<<gN, B, 0, stream>>>(x, degi, dinv, p, N);
        scatter1_k<<<gE, B, 0, stream>>>(src, dst, p, acc1, E);
        node2_k<<<gN, B, 0, stream>>>(dinv, p, acc1, W1, b1, W2, g, N);
        scatter2_k<<<gE, B, 0, stream>>>(src, dst, g, acc2, E);
        final_k<<<gN, B, 0, stream>>>(dinv, g, (const float2*)acc2, b2, out, N);
    }
}

// Round 6
// 267.359 us; speedup vs baseline: 3.7287x; 2.0189x over previous
//
#include <hip/hip_runtime.h>
#include <math.h>

// GCN 2-layer, algebraically collapsed (layer1 aggregates scalar p[n]=x[n]*dinv[n],
// layer2 aggregates 2-vec g[n]=dinv[n]*(relu(W1*s+b1)@W2)).
//
// Round-4 (540us): fill_k = 420us, bound by 4.8M global fetch-add atomics +
// scattered CSR writes (WRITE_SIZE 289MB, ~64B write-through per edge).
// Round-5: counting-sort binning with ZERO global atomics:
//   hist (LDS histo, coalesced out) -> scan -> replay-fill packed 4B records
//   -> per-bucket LDS-atomic aggregation with fused node math.

#define NNODES 100000
#define NEDGES 4800000
#define BN 128                 // nodes per bucket
#define NB 782                 // ceil(100000/128)
#define B1 1024                // binning blocks
#define CHUNK 4688             // ceil(NEDGES/B1)
#define SRC_BITS 17            // src < 100000 < 2^17
#define SRC_MASK 0x1FFFF

// ---- pass A: per-block bucket histogram (LDS atomics only) ----
__global__ __launch_bounds__(256) void hist_k(const int* __restrict__ dst,
                                              int* __restrict__ blockhist, int E) {
    __shared__ int h[NB];
    int blk = blockIdx.x;
    for (int i = threadIdx.x; i < NB; i += 256) h[i] = 0;
    __syncthreads();
    int lo = blk * CHUNK, hi = lo + CHUNK; if (hi > E) hi = E;
    for (int i = lo + threadIdx.x; i < hi; i += 256) atomicAdd(&h[dst[i] >> 7], 1);
    __syncthreads();
    int* row = blockhist + (size_t)blk * NB;
    for (int i = threadIdx.x; i < NB; i += 256) row[i] = h[i];
}

// ---- pass B1: per-bucket exclusive scan over the 1024 block counts ----
__global__ __launch_bounds__(256) void scanblk_k(const int* __restrict__ blockhist,
                                                 int* __restrict__ offs,
                                                 int* __restrict__ colsum) {
    int b = blockIdx.x, t = threadIdx.x;
    int v0 = blockhist[(size_t)(t * 4 + 0) * NB + b];
    int v1 = blockhist[(size_t)(t * 4 + 1) * NB + b];
    int v2 = blockhist[(size_t)(t * 4 + 2) * NB + b];
    int v3 = blockhist[(size_t)(t * 4 + 3) * NB + b];
    int s = v0 + v1 + v2 + v3;
    __shared__ int ps[256];
    ps[t] = s; __syncthreads();
    for (int off = 1; off < 256; off <<= 1) {
        int add = (t >= off) ? ps[t - off] : 0;
        __syncthreads();
        ps[t] += add;
        __syncthreads();
    }
    int run = ps[t] - s;  // exclusive
    offs[(size_t)(t * 4 + 0) * NB + b] = run; run += v0;
    offs[(size_t)(t * 4 + 1) * NB + b] = run; run += v1;
    offs[(size_t)(t * 4 + 2) * NB + b] = run; run += v2;
    offs[(size_t)(t * 4 + 3) * NB + b] = run; run += v3;
    if (t == 255) colsum[b] = run;
}

// ---- pass B2: exclusive scan of bucket totals -> bucket bases ----
__global__ __launch_bounds__(1024) void base_k(const int* __restrict__ colsum,
                                               int* __restrict__ bucketbase) {
    __shared__ int ps[1024];
    int t = threadIdx.x;
    int v = (t < NB) ? colsum[t] : 0;
    ps[t] = v; __syncthreads();
    for (int off = 1; off < 1024; off <<= 1) {
        int add = (t >= off) ? ps[t - off] : 0;
        __syncthreads();
        ps[t] += add;
        __syncthreads();
    }
    if (t < NB) bucketbase[t] = ps[t] - v;
}

// ---- pass C: replay + scatter packed records (LDS cursors, no global atomics) ----
__global__ __launch_bounds__(256) void binfill_k(const int* __restrict__ src,
                                                 const int* __restrict__ dst,
                                                 const int* __restrict__ offs,
                                                 const int* __restrict__ bucketbase,
                                                 unsigned* __restrict__ recs, int E) {
    __shared__ int cur[NB];
    int blk = blockIdx.x;
    const int* row = offs + (size_t)blk * NB;
    for (int i = threadIdx.x; i < NB; i += 256) cur[i] = bucketbase[i] + row[i];
    __syncthreads();
    int lo = blk * CHUNK, hi = lo + CHUNK; if (hi > E) hi = E;
    for (int i = lo + threadIdx.x; i < hi; i += 256) {
        int d = dst[i];
        int b = d >> 7;
        int pos = atomicAdd(&cur[b], 1);
        recs[pos] = (unsigned)src[i] | ((unsigned)(d & (BN - 1)) << SRC_BITS);
    }
}

// ---- pass D: per-bucket degree count + dinv + p (fused node1) ----
__global__ __launch_bounds__(512) void deg_k(const unsigned* __restrict__ recs,
                                             const int* __restrict__ bucketbase,
                                             const int* __restrict__ colsum,
                                             const float* __restrict__ x,
                                             float* __restrict__ dinv,
                                             float* __restrict__ p, int N) {
    int b = blockIdx.x;
    __shared__ int hh[BN];
    if (threadIdx.x < BN) hh[threadIdx.x] = 0;
    __syncthreads();
    int base = bucketbase[b], cnt = colsum[b];
    for (int i = threadIdx.x; i < cnt; i += 512) atomicAdd(&hh[recs[base + i] >> SRC_BITS], 1);
    __syncthreads();
    if (threadIdx.x < BN) {
        int n = b * BN + threadIdx.x;
        if (n < N) {
            float di = rsqrtf((float)(hh[threadIdx.x] + 1));  // +1 self-loop
            dinv[n] = di;
            p[n] = x[n] * di;
        }
    }
}

// ---- pass E: layer1 aggregate + fused 16-wide MLP -> g ----
__global__ __launch_bounds__(512) void agg1_k(const unsigned* __restrict__ recs,
                                              const int* __restrict__ bucketbase,
                                              const int* __restrict__ colsum,
                                              const float* __restrict__ dinv,
                                              const float* __restrict__ p,
                                              const float* __restrict__ W1,
                                              const float* __restrict__ b1,
                                              const float* __restrict__ W2,
                                              float2* __restrict__ g, int N) {
    int b = blockIdx.x;
    __shared__ float acc[BN];
    if (threadIdx.x < BN) acc[threadIdx.x] = 0.f;
    __syncthreads();
    int base = bucketbase[b], cnt = colsum[b];
    for (int i = threadIdx.x; i < cnt; i += 512) {
        unsigned r = recs[base + i];
        atomicAdd(&acc[r >> SRC_BITS], p[r & SRC_MASK]);
    }
    __syncthreads();
    if (threadIdx.x < BN) {
        int n = b * BN + threadIdx.x;
        if (n < N) {
            float di = dinv[n];
            float s = di * (p[n] + acc[threadIdx.x]);
            float g0 = 0.f, g1 = 0.f;
            #pragma unroll
            for (int k = 0; k < 16; ++k) {
                float h = fmaxf(fmaf(W1[k], s, b1[k]), 0.f);
                g0 = fmaf(h, W2[2 * k + 0], g0);
                g1 = fmaf(h, W2[2 * k + 1], g1);
            }
            g[n] = make_float2(g0 * di, g1 * di);
        }
    }
}

// ---- pass F: layer2 aggregate + fused bias/log_softmax -> out ----
__global__ __launch_bounds__(512) void agg2_k(const unsigned* __restrict__ recs,
                                              const int* __restrict__ bucketbase,
                                              const int* __restrict__ colsum,
                                              const float* __restrict__ dinv,
                                              const float2* __restrict__ g,
                                              const float* __restrict__ b2,
                                              float2* __restrict__ out, int N) {
    int b = blockIdx.x;
    __shared__ float a0[BN], a1[BN];
    if (threadIdx.x < BN) { a0[threadIdx.x] = 0.f; a1[threadIdx.x] = 0.f; }
    __syncthreads();
    int base = bucketbase[b], cnt = colsum[b];
    for (int i = threadIdx.x; i < cnt; i += 512) {
        unsigned r = recs[base + i];
        float2 gv = g[r & SRC_MASK];
        int li = r >> SRC_BITS;
        atomicAdd(&a0[li], gv.x);
        atomicAdd(&a1[li], gv.y);
    }
    __syncthreads();
    if (threadIdx.x < BN) {
        int n = b * BN + threadIdx.x;
        if (n < N) {
            float di = dinv[n];
            float2 gv = g[n];
            float o0 = fmaf(di, gv.x + a0[threadIdx.x], b2[0]);
            float o1 = fmaf(di, gv.y + a1[threadIdx.x], b2[1]);
            float m = fmaxf(o0, o1);
            float lse = m + logf(expf(o0 - m) + expf(o1 - m));
            out[n] = make_float2(o0 - lse, o1 - lse);
        }
    }
}

// ---------------- fallback atomic path (round-3 baseline) ----------------

__global__ void count_deg_k(const int* __restrict__ dst, int* __restrict__ degi, int E) {
    int i = blockIdx.x * blockDim.x + threadIdx.x;
    if (i < E) atomicAdd(&degi[dst[i]], 1);
}
__global__ void node1_k(const float* __restrict__ x, const int* __restrict__ degi,
                        float* __restrict__ dinv, float* __restrict__ p, int N) {
    int n = blockIdx.x * blockDim.x + threadIdx.x;
    if (n < N) {
        float di = rsqrtf((float)(degi[n] + 1));
        dinv[n] = di;
        p[n] = x[n] * di;
    }
}
__global__ void scatter1_k(const int* __restrict__ src, const int* __restrict__ dst,
                           const float* __restrict__ p, float* __restrict__ acc1, int E) {
    int i = blockIdx.x * blockDim.x + threadIdx.x;
    if (i < E) atomicAdd(&acc1[dst[i]], p[src[i]]);
}
__global__ void node2_k(const float* __restrict__ dinv, const float* __restrict__ p,
                        const float* __restrict__ acc1, const float* __restrict__ W1,
                        const float* __restrict__ b1, const float* __restrict__ W2,
                        float2* __restrict__ g, int N) {
    int n = blockIdx.x * blockDim.x + threadIdx.x;
    if (n < N) {
        float di = dinv[n];
        float s = di * (p[n] + acc1[n]);
        float g0 = 0.f, g1 = 0.f;
        #pragma unroll
        for (int k = 0; k < 16; ++k) {
            float h = fmaxf(fmaf(W1[k], s, b1[k]), 0.f);
            g0 = fmaf(h, W2[2 * k + 0], g0);
            g1 = fmaf(h, W2[2 * k + 1], g1);
        }
        g[n] = make_float2(g0 * di, g1 * di);
    }
}
__global__ void scatter2_k(const int* __restrict__ src, const int* __restrict__ dst,
                           const float2* __restrict__ g, float* __restrict__ acc2, int E) {
    int i = blockIdx.x * blockDim.x + threadIdx.x;
    if (i < E) {
        float2 gv = g[src[i]];
        int d = dst[i];
        atomicAdd(&acc2[2 * d + 0], gv.x);
        atomicAdd(&acc2[2 * d + 1], gv.y);
    }
}
__global__ void final_k(const float* __restrict__ dinv, const float2* __restrict__ g,
                        const float2* __restrict__ acc2, const float* __restrict__ b2,
                        float2* __restrict__ out, int N) {
    int n = blockIdx.x * blockDim.x + threadIdx.x;
    if (n < N) {
        float di = dinv[n];
        float2 gv = g[n];
        float2 av = acc2[n];
        float o0 = fmaf(di, gv.x + av.x, b2[0]);
        float o1 = fmaf(di, gv.y + av.y, b2[1]);
        float m = fmaxf(o0, o1);
        float lse = m + logf(expf(o0 - m) + expf(o1 - m));
        out[n] = make_float2(o0 - lse, o1 - lse);
    }
}

extern "C" void kernel_launch(void* const* d_in, const int* in_sizes, int n_in,
                              void* d_out, int out_size, void* d_ws, size_t ws_size,
                              hipStream_t stream) {
    const float* x  = (const float*)d_in[0];
    const int*   ei = (const int*)d_in[1];
    const float* W1 = (const float*)d_in[2];
    const float* b1 = (const float*)d_in[3];
    const float* W2 = (const float*)d_in[4];
    const float* b2 = (const float*)d_in[5];
    float2* out = (float2*)d_out;

    const int N = in_sizes[0];
    const int E = in_sizes[1] / 2;
    const int* src = ei;
    const int* dst = ei + E;

    // binned-path workspace layout
    size_t o_recs = 0;
    size_t o_bh   = o_recs + ((size_t)E * 4 + 255 & ~255UL);
    size_t o_offs = o_bh   + ((size_t)B1 * NB * 4 + 255 & ~255UL);
    size_t o_cs   = o_offs + ((size_t)B1 * NB * 4 + 255 & ~255UL);
    size_t o_bb   = o_cs   + ((size_t)NB * 4 + 255 & ~255UL);
    size_t o_dinv = o_bb   + ((size_t)NB * 4 + 255 & ~255UL);
    size_t o_p    = o_dinv + ((size_t)N * 4 + 255 & ~255UL);
    size_t o_g    = o_p    + ((size_t)N * 4 + 255 & ~255UL);
    size_t need   = o_g    + (size_t)N * 8;

    if (N == NNODES && E == NEDGES && ws_size >= need) {
        char* ws = (char*)d_ws;
        unsigned* recs = (unsigned*)(ws + o_recs);
        int* blockhist = (int*)(ws + o_bh);
        int* offs      = (int*)(ws + o_offs);
        int* colsum    = (int*)(ws + o_cs);
        int* bucketbase= (int*)(ws + o_bb);
        float* dinv    = (float*)(ws + o_dinv);
        float* p       = (float*)(ws + o_p);
        float2* g      = (float2*)(ws + o_g);

        hist_k   <<<B1, 256, 0, stream>>>(dst, blockhist, E);
        scanblk_k<<<NB, 256, 0, stream>>>(blockhist, offs, colsum);
        base_k   <<<1, 1024, 0, stream>>>(colsum, bucketbase);
        binfill_k<<<B1, 256, 0, stream>>>(src, dst, offs, bucketbase, recs, E);
        deg_k    <<<NB, 512, 0, stream>>>(recs, bucketbase, colsum, x, dinv, p, N);
        agg1_k   <<<NB, 512, 0, stream>>>(recs, bucketbase, colsum, dinv, p, W1, b1, W2, g, N);
        agg2_k   <<<NB, 512, 0, stream>>>(recs, bucketbase, colsum, dinv, g, b2, out, N);
    } else {
        // fallback: round-3 atomic pipeline
        char* ws = (char*)d_ws;
        int*    degi = (int*)(ws);
        float*  acc1 = (float*)(ws + 4UL * N);
        float*  acc2 = (float*)(ws + 8UL * N);
        float*  dinv = (float*)(ws + 16UL * N);
        float*  p    = (float*)(ws + 20UL * N);
        float2* g    = (float2*)(ws + 24UL * N);
        const int B = 256;
        const int gE = (E + B - 1) / B;
        const int gN = (N + B - 1) / B;
        hipMemsetAsync(ws, 0, 16UL * N, stream);
        count_deg_k<<<gE, B, 0, stream>>>(dst, degi, E);
        node1_k<<<gN, B, 0, stream>>>(x, degi, dinv, p, N);
        scatter1_k<<<gE, B, 0, stream>>>(src, dst, p, acc1, E);
        node2_k<<<gN, B, 0, stream>>>(dinv, p, acc1, W1, b1, W2, g, N);
        scatter2_k<<<gE, B, 0, stream>>>(src, dst, g, acc2, E);
        final_k<<<gN, B, 0, stream>>>(dinv, g, (const float2*)acc2, b2, out, N);
    }
}

// Round 12
// 243.556 us; speedup vs baseline: 4.0932x; 1.0977x over previous
//
#include <hip/hip_runtime.h>
#include <math.h>

// GCN 2-layer, algebraically collapsed (layer1 aggregates scalar p[n]=x[n]*dinv[n],
// layer2 aggregates 2-vec g[n]=dinv[n]*(relu(W1*s+b1)@W2)).
//
// Round-6 (267us): binfill_k 94us with 6.8x write amplification (WRITE_SIZE
// 130MB vs 19.2MB logical) -- runs of ~6 records per (block,bucket) left
// almost every 64B line partially filled. Round-7: BN=256 (NB=391 buckets),
// B1=512 binning blocks -> ~24-record (96B) runs, near-line-granule writes;
// 512-thread binning blocks for occupancy; agg kernels use 256 LDS counters.

#define NNODES 100000
#define NEDGES 4800000
#define BN 256                 // nodes per bucket
#define NB 391                 // ceil(100000/256)
#define B1 512                 // binning blocks
#define CHUNK 9375             // 4800000/512 exact
#define SRC_BITS 17            // src < 100000 < 2^17
#define SRC_MASK 0x1FFFF

// ---- pass A: per-block bucket histogram (LDS atomics only) ----
__global__ __launch_bounds__(512) void hist_k(const int* __restrict__ dst,
                                              int* __restrict__ blockhist, int E) {
    __shared__ int h[NB];
    int blk = blockIdx.x;
    for (int i = threadIdx.x; i < NB; i += 512) h[i] = 0;
    __syncthreads();
    int lo = blk * CHUNK, hi = lo + CHUNK; if (hi > E) hi = E;
    for (int i = lo + threadIdx.x; i < hi; i += 512) atomicAdd(&h[dst[i] >> 8], 1);
    __syncthreads();
    int* row = blockhist + (size_t)blk * NB;
    for (int i = threadIdx.x; i < NB; i += 512) row[i] = h[i];
}

// ---- pass B1: per-bucket exclusive scan over the 512 block counts ----
__global__ __launch_bounds__(512) void scanblk_k(const int* __restrict__ blockhist,
                                                 int* __restrict__ offs,
                                                 int* __restrict__ colsum) {
    int b = blockIdx.x, t = threadIdx.x;   // t indexes the binning block
    int v = blockhist[(size_t)t * NB + b];
    __shared__ int ps[512];
    ps[t] = v; __syncthreads();
    for (int off = 1; off < 512; off <<= 1) {
        int add = (t >= off) ? ps[t - off] : 0;
        __syncthreads();
        ps[t] += add;
        __syncthreads();
    }
    offs[(size_t)t * NB + b] = ps[t] - v;   // exclusive
    if (t == 511) colsum[b] = ps[t];
}

// ---- pass B2: exclusive scan of bucket totals -> bucket bases ----
__global__ __launch_bounds__(512) void base_k(const int* __restrict__ colsum,
                                              int* __restrict__ bucketbase) {
    __shared__ int ps[512];
    int t = threadIdx.x;
    int v = (t < NB) ? colsum[t] : 0;
    ps[t] = v; __syncthreads();
    for (int off = 1; off < 512; off <<= 1) {
        int add = (t >= off) ? ps[t - off] : 0;
        __syncthreads();
        ps[t] += add;
        __syncthreads();
    }
    if (t < NB) bucketbase[t] = ps[t] - v;
}

// ---- pass C: replay + scatter packed records (LDS cursors, no global atomics) ----
__global__ __launch_bounds__(512) void binfill_k(const int* __restrict__ src,
                                                 const int* __restrict__ dst,
                                                 const int* __restrict__ offs,
                                                 const int* __restrict__ bucketbase,
                                                 unsigned* __restrict__ recs, int E) {
    __shared__ int cur[NB];
    int blk = blockIdx.x;
    const int* row = offs + (size_t)blk * NB;
    for (int i = threadIdx.x; i < NB; i += 512) cur[i] = bucketbase[i] + row[i];
    __syncthreads();
    int lo = blk * CHUNK, hi = lo + CHUNK; if (hi > E) hi = E;
    for (int i = lo + threadIdx.x; i < hi; i += 512) {
        int d = dst[i];
        int b = d >> 8;
        int pos = atomicAdd(&cur[b], 1);
        recs[pos] = (unsigned)src[i] | ((unsigned)(d & (BN - 1)) << SRC_BITS);
    }
}

// ---- pass D: per-bucket degree count + dinv + p (fused node1) ----
__global__ __launch_bounds__(512) void deg_k(const unsigned* __restrict__ recs,
                                             const int* __restrict__ bucketbase,
                                             const int* __restrict__ colsum,
                                             const float* __restrict__ x,
                                             float* __restrict__ dinv,
                                             float* __restrict__ p, int N) {
    int b = blockIdx.x;
    __shared__ int hh[BN];
    if (threadIdx.x < BN) hh[threadIdx.x] = 0;
    __syncthreads();
    int base = bucketbase[b], cnt = colsum[b];
    for (int i = threadIdx.x; i < cnt; i += 512) atomicAdd(&hh[recs[base + i] >> SRC_BITS], 1);
    __syncthreads();
    if (threadIdx.x < BN) {
        int n = b * BN + threadIdx.x;
        if (n < N) {
            float di = rsqrtf((float)(hh[threadIdx.x] + 1));  // +1 self-loop
            dinv[n] = di;
            p[n] = x[n] * di;
        }
    }
}

// ---- pass E: layer1 aggregate + fused 16-wide MLP -> g ----
__global__ __launch_bounds__(512) void agg1_k(const unsigned* __restrict__ recs,
                                              const int* __restrict__ bucketbase,
                                              const int* __restrict__ colsum,
                                              const float* __restrict__ dinv,
                                              const float* __restrict__ p,
                                              const float* __restrict__ W1,
                                              const float* __restrict__ b1,
                                              const float* __restrict__ W2,
                                              float2* __restrict__ g, int N) {
    int b = blockIdx.x;
    __shared__ float acc[BN];
    if (threadIdx.x < BN) acc[threadIdx.x] = 0.f;
    __syncthreads();
    int base = bucketbase[b], cnt = colsum[b];
    for (int i = threadIdx.x; i < cnt; i += 512) {
        unsigned r = recs[base + i];
        atomicAdd(&acc[r >> SRC_BITS], p[r & SRC_MASK]);
    }
    __syncthreads();
    if (threadIdx.x < BN) {
        int n = b * BN + threadIdx.x;
        if (n < N) {
            float di = dinv[n];
            float s = di * (p[n] + acc[threadIdx.x]);
            float g0 = 0.f, g1 = 0.f;
            #pragma unroll
            for (int k = 0; k < 16; ++k) {
                float h = fmaxf(fmaf(W1[k], s, b1[k]), 0.f);
                g0 = fmaf(h, W2[2 * k + 0], g0);
                g1 = fmaf(h, W2[2 * k + 1], g1);
            }
            g[n] = make_float2(g0 * di, g1 * di);
        }
    }
}

// ---- pass F: layer2 aggregate + fused bias/log_softmax -> out ----
__global__ __launch_bounds__(512) void agg2_k(const unsigned* __restrict__ recs,
                                              const int* __restrict__ bucketbase,
                                              const int* __restrict__ colsum,
                                              const float* __restrict__ dinv,
                                              const float2* __restrict__ g,
                                              const float* __restrict__ b2,
                                              float2* __restrict__ out, int N) {
    int b = blockIdx.x;
    __shared__ float a0[BN], a1[BN];
    if (threadIdx.x < BN) { a0[threadIdx.x] = 0.f; a1[threadIdx.x] = 0.f; }
    __syncthreads();
    int base = bucketbase[b], cnt = colsum[b];
    for (int i = threadIdx.x; i < cnt; i += 512) {
        unsigned r = recs[base + i];
        float2 gv = g[r & SRC_MASK];
        int li = r >> SRC_BITS;
        atomicAdd(&a0[li], gv.x);
        atomicAdd(&a1[li], gv.y);
    }
    __syncthreads();
    if (threadIdx.x < BN) {
        int n = b * BN + threadIdx.x;
        if (n < N) {
            float di = dinv[n];
            float2 gv = g[n];
            float o0 = fmaf(di, gv.x + a0[threadIdx.x], b2[0]);
            float o1 = fmaf(di, gv.y + a1[threadIdx.x], b2[1]);
            float m = fmaxf(o0, o1);
            float lse = m + logf(expf(o0 - m) + expf(o1 - m));
            out[n] = make_float2(o0 - lse, o1 - lse);
        }
    }
}

// ---------------- fallback atomic path (round-3 baseline) ----------------

__global__ void count_deg_k(const int* __restrict__ dst, int* __restrict__ degi, int E) {
    int i = blockIdx.x * blockDim.x + threadIdx.x;
    if (i < E) atomicAdd(&degi[dst[i]], 1);
}
__global__ void node1_k(const float* __restrict__ x, const int* __restrict__ degi,
                        float* __restrict__ dinv, float* __restrict__ p, int N) {
    int n = blockIdx.x * blockDim.x + threadIdx.x;
    if (n < N) {
        float di = rsqrtf((float)(degi[n] + 1));
        dinv[n] = di;
        p[n] = x[n] * di;
    }
}
__global__ void scatter1_k(const int* __restrict__ src, const int* __restrict__ dst,
                           const float* __restrict__ p, float* __restrict__ acc1, int E) {
    int i = blockIdx.x * blockDim.x + threadIdx.x;
    if (i < E) atomicAdd(&acc1[dst[i]], p[src[i]]);
}
__global__ void node2_k(const float* __restrict__ dinv, const float* __restrict__ p,
                        const float* __restrict__ acc1, const float* __restrict__ W1,
                        const float* __restrict__ b1, const float* __restrict__ W2,
                        float2* __restrict__ g, int N) {
    int n = blockIdx.x * blockDim.x + threadIdx.x;
    if (n < N) {
        float di = dinv[n];
        float s = di * (p[n] + acc1[n]);
        float g0 = 0.f, g1 = 0.f;
        #pragma unroll
        for (int k = 0; k < 16; ++k) {
            float h = fmaxf(fmaf(W1[k], s, b1[k]), 0.f);
            g0 = fmaf(h, W2[2 * k + 0], g0);
            g1 = fmaf(h, W2[2 * k + 1], g1);
        }
        g[n] = make_float2(g0 * di, g1 * di);
    }
}
__global__ void scatter2_k(const int* __restrict__ src, const int* __restrict__ dst,
                           const float2* __restrict__ g, float* __restrict__ acc2, int E) {
    int i = blockIdx.x * blockDim.x + threadIdx.x;
    if (i < E) {
        float2 gv = g[src[i]];
        int d = dst[i];
        atomicAdd(&acc2[2 * d + 0], gv.x);
        atomicAdd(&acc2[2 * d + 1], gv.y);
    }
}
__global__ void final_k(const float* __restrict__ dinv, const float2* __restrict__ g,
                        const float2* __restrict__ acc2, const float* __restrict__ b2,
                        float2* __restrict__ out, int N) {
    int n = blockIdx.x * blockDim.x + threadIdx.x;
    if (n < N) {
        float di = dinv[n];
        float2 gv = g[n];
        float2 av = acc2[n];
        float o0 = fmaf(di, gv.x + av.x, b2[0]);
        float o1 = fmaf(di, gv.y + av.y, b2[1]);
        float m = fmaxf(o0, o1);
        float lse = m + logf(expf(o0 - m) + expf(o1 - m));
        out[n] = make_float2(o0 - lse, o1 - lse);
    }
}

extern "C" void kernel_launch(void* const* d_in, const int* in_sizes, int n_in,
                              void* d_out, int out_size, void* d_ws, size_t ws_size,
                              hipStream_t stream) {
    const float* x  = (const float*)d_in[0];
    const int*   ei = (const int*)d_in[1];
    const float* W1 = (const float*)d_in[2];
    const float* b1 = (const float*)d_in[3];
    const float* W2 = (const float*)d_in[4];
    const float* b2 = (const float*)d_in[5];
    float2* out = (float2*)d_out;

    const int N = in_sizes[0];
    const int E = in_sizes[1] / 2;
    const int* src = ei;
    const int* dst = ei + E;

    // binned-path workspace layout
    size_t o_recs = 0;
    size_t o_bh   = o_recs + ((size_t)E * 4 + 255 & ~255UL);
    size_t o_offs = o_bh   + ((size_t)B1 * NB * 4 + 255 & ~255UL);
    size_t o_cs   = o_offs + ((size_t)B1 * NB * 4 + 255 & ~255UL);
    size_t o_bb   = o_cs   + ((size_t)NB * 4 + 255 & ~255UL);
    size_t o_dinv = o_bb   + ((size_t)NB * 4 + 255 & ~255UL);
    size_t o_p    = o_dinv + ((size_t)N * 4 + 255 & ~255UL);
    size_t o_g    = o_p    + ((size_t)N * 4 + 255 & ~255UL);
    size_t need   = o_g    + (size_t)N * 8;

    if (N == NNODES && E == NEDGES && ws_size >= need) {
        char* ws = (char*)d_ws;
        unsigned* recs = (unsigned*)(ws + o_recs);
        int* blockhist = (int*)(ws + o_bh);
        int* offs      = (int*)(ws + o_offs);
        int* colsum    = (int*)(ws + o_cs);
        int* bucketbase= (int*)(ws + o_bb);
        float* dinv    = (float*)(ws + o_dinv);
        float* p       = (float*)(ws + o_p);
        float2* g      = (float2*)(ws + o_g);

        hist_k   <<<B1, 512, 0, stream>>>(dst, blockhist, E);
        scanblk_k<<<NB, 512, 0, stream>>>(blockhist, offs, colsum);
        base_k   <<<1, 512, 0, stream>>>(colsum, bucketbase);
        binfill_k<<<B1, 512, 0, stream>>>(src, dst, offs, bucketbase, recs, E);
        deg_k    <<<NB, 512, 0, stream>>>(recs, bucketbase, colsum, x, dinv, p, N);
        agg1_k   <<<NB, 512, 0, stream>>>(recs, bucketbase, colsum, dinv, p, W1, b1, W2, g, N);
        agg2_k   <<<NB, 512, 0, stream>>>(recs, bucketbase, colsum, dinv, g, b2, out, N);
    } else {
        // fallback: round-3 atomic pipeline
        char* ws = (char*)d_ws;
        int*    degi = (int*)(ws);
        float*  acc1 = (float*)(ws + 4UL * N);
        float*  acc2 = (float*)(ws + 8UL * N);
        float*  dinv = (float*)(ws + 16UL * N);
        float*  p    = (float*)(ws + 20UL * N);
        float2* g    = (float2*)(ws + 24UL * N);
        const int B = 256;
        const int gE = (E + B - 1) / B;
        const int gN = (N + B - 1) / B;
        hipMemsetAsync(ws, 0, 16UL * N, stream);
        count_deg_k<<<gE, B, 0, stream>>>(dst, degi, E);
        node1_k<<<gN, B, 0, stream>>>(x, degi, dinv, p, N);
        scatter1_k<<<gE, B, 0, stream>>>(src, dst, p, acc1, E);
        node2_k<<<gN, B, 0, stream>>>(dinv, p, acc1, W1, b1, W2, g, N);
        scatter2_k<<<gE, B, 0, stream>>>(src, dst, g, acc2, E);
        final_k<<<gN, B, 0, stream>>>(dinv, g, (const float2*)acc2, b2, out, N);
    }
}

// Round 13
// 238.362 us; speedup vs baseline: 4.1824x; 1.0218x over previous
//
#include <hip/hip_runtime.h>
#include <math.h>

// GCN 2-layer, algebraically collapsed (layer1 aggregates scalar p[n]=x[n]*dinv[n],
// layer2 aggregates 2-vec g[n]=dinv[n]*(relu(W1*s+b1)@W2)).
//
// Round-12 (244us): agg2_k=68us, VALUBusy 1.4%, occupancy 23% -> the per-bucket
// aggregation kernels (deg/agg1/agg2) are latency-bound with only 391 blocks
// (1.5/CU). Round-13: split each bucket across SEG=4 blocks (1564 blocks,
// 100% occupancy); segment kernels write LDS partials coalesced to global
// (no atomics), tiny combine kernels sum partials + fused node math.

#define NNODES 100000
#define NEDGES 4800000
#define BN 256                 // nodes per bucket
#define NB 391                 // ceil(100000/256)
#define NPAD (NB * BN)         // 100096 padded node count
#define B1 512                 // binning blocks
#define CHUNK 9375             // 4800000/512 exact
#define SEG 4                  // segment blocks per bucket
#define SRC_BITS 17            // src < 100000 < 2^17
#define SRC_MASK 0x1FFFF

// ---- pass A: per-block bucket histogram (LDS atomics only) ----
__global__ __launch_bounds__(512) void hist_k(const int* __restrict__ dst,
                                              int* __restrict__ blockhist, int E) {
    __shared__ int h[NB];
    int blk = blockIdx.x;
    for (int i = threadIdx.x; i < NB; i += 512) h[i] = 0;
    __syncthreads();
    int lo = blk * CHUNK, hi = lo + CHUNK; if (hi > E) hi = E;
    for (int i = lo + threadIdx.x; i < hi; i += 512) atomicAdd(&h[dst[i] >> 8], 1);
    __syncthreads();
    int* row = blockhist + (size_t)blk * NB;
    for (int i = threadIdx.x; i < NB; i += 512) row[i] = h[i];
}

// ---- pass B1: per-bucket exclusive scan over the 512 block counts ----
__global__ __launch_bounds__(512) void scanblk_k(const int* __restrict__ blockhist,
                                                 int* __restrict__ offs,
                                                 int* __restrict__ colsum) {
    int b = blockIdx.x, t = threadIdx.x;   // t indexes the binning block
    int v = blockhist[(size_t)t * NB + b];
    __shared__ int ps[512];
    ps[t] = v; __syncthreads();
    for (int off = 1; off < 512; off <<= 1) {
        int add = (t >= off) ? ps[t - off] : 0;
        __syncthreads();
        ps[t] += add;
        __syncthreads();
    }
    offs[(size_t)t * NB + b] = ps[t] - v;   // exclusive
    if (t == 511) colsum[b] = ps[t];
}

// ---- pass B2: exclusive scan of bucket totals -> bucket bases ----
__global__ __launch_bounds__(512) void base_k(const int* __restrict__ colsum,
                                              int* __restrict__ bucketbase) {
    __shared__ int ps[512];
    int t = threadIdx.x;
    int v = (t < NB) ? colsum[t] : 0;
    ps[t] = v; __syncthreads();
    for (int off = 1; off < 512; off <<= 1) {
        int add = (t >= off) ? ps[t - off] : 0;
        __syncthreads();
        ps[t] += add;
        __syncthreads();
    }
    if (t < NB) bucketbase[t] = ps[t] - v;
}

// ---- pass C: replay + scatter packed records (LDS cursors, no global atomics) ----
__global__ __launch_bounds__(512) void binfill_k(const int* __restrict__ src,
                                                 const int* __restrict__ dst,
                                                 const int* __restrict__ offs,
                                                 const int* __restrict__ bucketbase,
                                                 unsigned* __restrict__ recs, int E) {
    __shared__ int cur[NB];
    int blk = blockIdx.x;
    const int* row = offs + (size_t)blk * NB;
    for (int i = threadIdx.x; i < NB; i += 512) cur[i] = bucketbase[i] + row[i];
    __syncthreads();
    int lo = blk * CHUNK, hi = lo + CHUNK; if (hi > E) hi = E;
    for (int i = lo + threadIdx.x; i < hi; i += 512) {
        int d = dst[i];
        int b = d >> 8;
        int pos = atomicAdd(&cur[b], 1);
        recs[pos] = (unsigned)src[i] | ((unsigned)(d & (BN - 1)) << SRC_BITS);
    }
}

// ---- pass D: degree partials (SEG blocks per bucket) ----
__global__ __launch_bounds__(512) void deg_s_k(const unsigned* __restrict__ recs,
                                               const int* __restrict__ bucketbase,
                                               const int* __restrict__ colsum,
                                               int* __restrict__ dpart) {
    int blk = blockIdx.x;
    int b = blk >> 2, sg = blk & (SEG - 1);
    __shared__ int hh[BN];
    if (threadIdx.x < BN) hh[threadIdx.x] = 0;
    __syncthreads();
    int base = bucketbase[b], cnt = colsum[b];
    int lo = base + (int)((long long)cnt * sg / SEG);
    int hi = base + (int)((long long)cnt * (sg + 1) / SEG);
    for (int i = lo + threadIdx.x; i < hi; i += 512)
        atomicAdd(&hh[recs[i] >> SRC_BITS], 1);
    __syncthreads();
    if (threadIdx.x < BN)
        dpart[(size_t)sg * NPAD + b * BN + threadIdx.x] = hh[threadIdx.x];
}

__global__ __launch_bounds__(512) void deg_c_k(const float* __restrict__ x,
                                               const int* __restrict__ dpart,
                                               float* __restrict__ dinv,
                                               float* __restrict__ p, int N) {
    int n = blockIdx.x * blockDim.x + threadIdx.x;
    if (n < N) {
        int d = dpart[n] + dpart[NPAD + n] + dpart[2 * NPAD + n] + dpart[3 * NPAD + n];
        float di = rsqrtf((float)(d + 1));   // +1 self-loop
        dinv[n] = di;
        p[n] = x[n] * di;
    }
}

// ---- pass E: layer1 aggregate partials + combine (fused MLP -> g) ----
__global__ __launch_bounds__(512) void agg1_s_k(const unsigned* __restrict__ recs,
                                                const int* __restrict__ bucketbase,
                                                const int* __restrict__ colsum,
                                                const float* __restrict__ p,
                                                float* __restrict__ a1part) {
    int blk = blockIdx.x;
    int b = blk >> 2, sg = blk & (SEG - 1);
    __shared__ float acc[BN];
    if (threadIdx.x < BN) acc[threadIdx.x] = 0.f;
    __syncthreads();
    int base = bucketbase[b], cnt = colsum[b];
    int lo = base + (int)((long long)cnt * sg / SEG);
    int hi = base + (int)((long long)cnt * (sg + 1) / SEG);
    for (int i = lo + threadIdx.x; i < hi; i += 512) {
        unsigned r = recs[i];
        atomicAdd(&acc[r >> SRC_BITS], p[r & SRC_MASK]);
    }
    __syncthreads();
    if (threadIdx.x < BN)
        a1part[(size_t)sg * NPAD + b * BN + threadIdx.x] = acc[threadIdx.x];
}

__global__ __launch_bounds__(512) void agg1_c_k(const float* __restrict__ dinv,
                                                const float* __restrict__ p,
                                                const float* __restrict__ a1part,
                                                const float* __restrict__ W1,
                                                const float* __restrict__ b1,
                                                const float* __restrict__ W2,
                                                float2* __restrict__ g, int N) {
    int n = blockIdx.x * blockDim.x + threadIdx.x;
    if (n < N) {
        float sum = a1part[n] + a1part[NPAD + n] + a1part[2 * NPAD + n] + a1part[3 * NPAD + n];
        float di = dinv[n];
        float s = di * (p[n] + sum);
        float g0 = 0.f, g1 = 0.f;
        #pragma unroll
        for (int k = 0; k < 16; ++k) {
            float h = fmaxf(fmaf(W1[k], s, b1[k]), 0.f);
            g0 = fmaf(h, W2[2 * k + 0], g0);
            g1 = fmaf(h, W2[2 * k + 1], g1);
        }
        g[n] = make_float2(g0 * di, g1 * di);
    }
}

// ---- pass F: layer2 aggregate partials + combine (fused log_softmax -> out) ----
__global__ __launch_bounds__(512) void agg2_s_k(const unsigned* __restrict__ recs,
                                                const int* __restrict__ bucketbase,
                                                const int* __restrict__ colsum,
                                                const float2* __restrict__ g,
                                                float2* __restrict__ a2part) {
    int blk = blockIdx.x;
    int b = blk >> 2, sg = blk & (SEG - 1);
    __shared__ float a0[BN], a1[BN];
    if (threadIdx.x < BN) { a0[threadIdx.x] = 0.f; a1[threadIdx.x] = 0.f; }
    __syncthreads();
    int base = bucketbase[b], cnt = colsum[b];
    int lo = base + (int)((long long)cnt * sg / SEG);
    int hi = base + (int)((long long)cnt * (sg + 1) / SEG);
    for (int i = lo + threadIdx.x; i < hi; i += 512) {
        unsigned r = recs[i];
        float2 gv = g[r & SRC_MASK];
        int li = r >> SRC_BITS;
        atomicAdd(&a0[li], gv.x);
        atomicAdd(&a1[li], gv.y);
    }
    __syncthreads();
    if (threadIdx.x < BN)
        a2part[(size_t)sg * NPAD + b * BN + threadIdx.x] =
            make_float2(a0[threadIdx.x], a1[threadIdx.x]);
}

__global__ __launch_bounds__(512) void agg2_c_k(const float* __restrict__ dinv,
                                                const float2* __restrict__ g,
                                                const float2* __restrict__ a2part,
                                                const float* __restrict__ b2,
                                                float2* __restrict__ out, int N) {
    int n = blockIdx.x * blockDim.x + threadIdx.x;
    if (n < N) {
        float2 q0 = a2part[n], q1 = a2part[NPAD + n];
        float2 q2 = a2part[2 * NPAD + n], q3 = a2part[3 * NPAD + n];
        float s0 = q0.x + q1.x + q2.x + q3.x;
        float s1 = q0.y + q1.y + q2.y + q3.y;
        float di = dinv[n];
        float2 gv = g[n];
        float o0 = fmaf(di, gv.x + s0, b2[0]);
        float o1 = fmaf(di, gv.y + s1, b2[1]);
        float m = fmaxf(o0, o1);
        float lse = m + logf(expf(o0 - m) + expf(o1 - m));
        out[n] = make_float2(o0 - lse, o1 - lse);
    }
}

// ---------------- fallback atomic path (round-3 baseline) ----------------

__global__ void count_deg_k(const int* __restrict__ dst, int* __restrict__ degi, int E) {
    int i = blockIdx.x * blockDim.x + threadIdx.x;
    if (i < E) atomicAdd(&degi[dst[i]], 1);
}
__global__ void node1_k(const float* __restrict__ x, const int* __restrict__ degi,
                        float* __restrict__ dinv, float* __restrict__ p, int N) {
    int n = blockIdx.x * blockDim.x + threadIdx.x;
    if (n < N) {
        float di = rsqrtf((float)(degi[n] + 1));
        dinv[n] = di;
        p[n] = x[n] * di;
    }
}
__global__ void scatter1_k(const int* __restrict__ src, const int* __restrict__ dst,
                           const float* __restrict__ p, float* __restrict__ acc1, int E) {
    int i = blockIdx.x * blockDim.x + threadIdx.x;
    if (i < E) atomicAdd(&acc1[dst[i]], p[src[i]]);
}
__global__ void node2_k(const float* __restrict__ dinv, const float* __restrict__ p,
                        const float* __restrict__ acc1, const float* __restrict__ W1,
                        const float* __restrict__ b1, const float* __restrict__ W2,
                        float2* __restrict__ g, int N) {
    int n = blockIdx.x * blockDim.x + threadIdx.x;
    if (n < N) {
        float di = dinv[n];
        float s = di * (p[n] + acc1[n]);
        float g0 = 0.f, g1 = 0.f;
        #pragma unroll
        for (int k = 0; k < 16; ++k) {
            float h = fmaxf(fmaf(W1[k], s, b1[k]), 0.f);
            g0 = fmaf(h, W2[2 * k + 0], g0);
            g1 = fmaf(h, W2[2 * k + 1], g1);
        }
        g[n] = make_float2(g0 * di, g1 * di);
    }
}
__global__ void scatter2_k(const int* __restrict__ src, const int* __restrict__ dst,
                           const float2* __restrict__ g, float* __restrict__ acc2, int E) {
    int i = blockIdx.x * blockDim.x + threadIdx.x;
    if (i < E) {
        float2 gv = g[src[i]];
        int d = dst[i];
        atomicAdd(&acc2[2 * d + 0], gv.x);
        atomicAdd(&acc2[2 * d + 1], gv.y);
    }
}
__global__ void final_k(const float* __restrict__ dinv, const float2* __restrict__ g,
                        const float2* __restrict__ acc2, const float* __restrict__ b2,
                        float2* __restrict__ out, int N) {
    int n = blockIdx.x * blockDim.x + threadIdx.x;
    if (n < N) {
        float di = dinv[n];
        float2 gv = g[n];
        float2 av = acc2[n];
        float o0 = fmaf(di, gv.x + av.x, b2[0]);
        float o1 = fmaf(di, gv.y + av.y, b2[1]);
        float m = fmaxf(o0, o1);
        float lse = m + logf(expf(o0 - m) + expf(o1 - m));
        out[n] = make_float2(o0 - lse, o1 - lse);
    }
}

extern "C" void kernel_launch(void* const* d_in, const int* in_sizes, int n_in,
                              void* d_out, int out_size, void* d_ws, size_t ws_size,
                              hipStream_t stream) {
    const float* x  = (const float*)d_in[0];
    const int*   ei = (const int*)d_in[1];
    const float* W1 = (const float*)d_in[2];
    const float* b1 = (const float*)d_in[3];
    const float* W2 = (const float*)d_in[4];
    const float* b2 = (const float*)d_in[5];
    float2* out = (float2*)d_out;

    const int N = in_sizes[0];
    const int E = in_sizes[1] / 2;
    const int* src = ei;
    const int* dst = ei + E;

    // binned-path workspace layout
    size_t o_recs = 0;
    size_t o_bh   = o_recs + ((size_t)E * 4 + 255 & ~255UL);
    size_t o_offs = o_bh   + ((size_t)B1 * NB * 4 + 255 & ~255UL);
    size_t o_cs   = o_offs + ((size_t)B1 * NB * 4 + 255 & ~255UL);
    size_t o_bb   = o_cs   + ((size_t)NB * 4 + 255 & ~255UL);
    size_t o_dinv = o_bb   + ((size_t)NB * 4 + 255 & ~255UL);
    size_t o_p    = o_dinv + ((size_t)N * 4 + 255 & ~255UL);
    size_t o_g    = o_p    + ((size_t)N * 4 + 255 & ~255UL);
    size_t o_dp   = o_g    + ((size_t)N * 8 + 255 & ~255UL);
    size_t o_a1p  = o_dp   + ((size_t)SEG * NPAD * 4 + 255 & ~255UL);
    size_t o_a2p  = o_a1p  + ((size_t)SEG * NPAD * 4 + 255 & ~255UL);
    size_t need   = o_a2p  + (size_t)SEG * NPAD * 8;

    if (N == NNODES && E == NEDGES && ws_size >= need) {
        char* ws = (char*)d_ws;
        unsigned* recs = (unsigned*)(ws + o_recs);
        int* blockhist = (int*)(ws + o_bh);
        int* offs      = (int*)(ws + o_offs);
        int* colsum    = (int*)(ws + o_cs);
        int* bucketbase= (int*)(ws + o_bb);
        float* dinv    = (float*)(ws + o_dinv);
        float* p       = (float*)(ws + o_p);
        float2* g      = (float2*)(ws + o_g);
        int* dpart     = (int*)(ws + o_dp);
        float* a1part  = (float*)(ws + o_a1p);
        float2* a2part = (float2*)(ws + o_a2p);

        const int gN = (N + 511) / 512;
        hist_k   <<<B1, 512, 0, stream>>>(dst, blockhist, E);
        scanblk_k<<<NB, 512, 0, stream>>>(blockhist, offs, colsum);
        base_k   <<<1, 512, 0, stream>>>(colsum, bucketbase);
        binfill_k<<<B1, 512, 0, stream>>>(src, dst, offs, bucketbase, recs, E);
        deg_s_k  <<<NB * SEG, 512, 0, stream>>>(recs, bucketbase, colsum, dpart);
        deg_c_k  <<<gN, 512, 0, stream>>>(x, dpart, dinv, p, N);
        agg1_s_k <<<NB * SEG, 512, 0, stream>>>(recs, bucketbase, colsum, p, a1part);
        agg1_c_k <<<gN, 512, 0, stream>>>(dinv, p, a1part, W1, b1, W2, g, N);
        agg2_s_k <<<NB * SEG, 512, 0, stream>>>(recs, bucketbase, colsum, g, a2part);
        agg2_c_k <<<gN, 512, 0, stream>>>(dinv, g, a2part, b2, out, N);
    } else {
        // fallback: round-3 atomic pipeline
        char* ws = (char*)d_ws;
        int*    degi = (int*)(ws);
        float*  acc1 = (float*)(ws + 4UL * N);
        float*  acc2 = (float*)(ws + 8UL * N);
        float*  dinvf= (float*)(ws + 16UL * N);
        float*  pf   = (float*)(ws + 20UL * N);
        float2* gf   = (float2*)(ws + 24UL * N);
        const int B = 256;
        const int gE = (E + B - 1) / B;
        const int gNf = (N + B - 1) / B;
        hipMemsetAsync(ws, 0, 16UL * N, stream);
        count_deg_k<<<gE, B, 0, stream>>>(dst, degi, E);
        node1_k<<<gNf, B, 0, stream>>>(x, degi, dinvf, pf, N);
        scatter1_k<<<gE, B, 0, stream>>>(src, dst, pf, acc1, E);
        node2_k<<<gNf, B, 0, stream>>>(dinvf, pf, acc1, W1, b1, W2, gf, N);
        scatter2_k<<<gE, B, 0, stream>>>(src, dst, gf, acc2, E);
        final_k<<<gNf, B, 0, stream>>>(dinvf, gf, (const float2*)acc2, b2, out, N);
    }
}

// Round 14
// 228.015 us; speedup vs baseline: 4.3722x; 1.0454x over previous
//
#include <hip/hip_runtime.h>
#include <math.h>

// GCN 2-layer, algebraically collapsed (layer1 aggregates scalar p[n]=x[n]*dinv[n],
// layer2 aggregates 2-vec g[n]=dinv[n]*(relu(W1*s+b1)@W2)).
//
// Round-13 (238us): binfill_k 69us, WRITE_SIZE ~100MB vs 19.2MB logical (5x):
// LDS-cursor scatter interleaves bucket runs in TIME (each wave's 64 stores hit
// 64 buckets), keeping ~800 partial lines live per block -> L2 evicts
// partially-dirty lines repeatedly. Round-14: local-sort binfill — scatter the
// chunk into LDS (sorted by bucket), then write out linearly (consecutive
// threads -> consecutive addresses; each line dirtied in one burst).

#define NNODES 100000
#define NEDGES 4800000
#define BN 256                 // nodes per bucket
#define NB 391                 // ceil(100000/256)
#define NPAD (NB * BN)         // 100096 padded node count
#define B1 512                 // binning blocks
#define CHUNK 9375             // 4800000/512 exact
#define SEG 4                  // segment blocks per bucket
#define SRC_BITS 17            // src < 100000 < 2^17
#define SRC_MASK 0x1FFFF

// ---- pass A: per-block bucket histogram (LDS atomics only) ----
__global__ __launch_bounds__(512) void hist_k(const int* __restrict__ dst,
                                              int* __restrict__ blockhist, int E) {
    __shared__ int h[NB];
    int blk = blockIdx.x;
    for (int i = threadIdx.x; i < NB; i += 512) h[i] = 0;
    __syncthreads();
    int lo = blk * CHUNK, hi = lo + CHUNK; if (hi > E) hi = E;
    for (int i = lo + threadIdx.x; i < hi; i += 512) atomicAdd(&h[dst[i] >> 8], 1);
    __syncthreads();
    int* row = blockhist + (size_t)blk * NB;
    for (int i = threadIdx.x; i < NB; i += 512) row[i] = h[i];
}

// ---- pass B1: per-bucket exclusive scan over the 512 block counts ----
__global__ __launch_bounds__(512) void scanblk_k(const int* __restrict__ blockhist,
                                                 int* __restrict__ offs,
                                                 int* __restrict__ colsum) {
    int b = blockIdx.x, t = threadIdx.x;   // t indexes the binning block
    int v = blockhist[(size_t)t * NB + b];
    __shared__ int ps[512];
    ps[t] = v; __syncthreads();
    for (int off = 1; off < 512; off <<= 1) {
        int add = (t >= off) ? ps[t - off] : 0;
        __syncthreads();
        ps[t] += add;
        __syncthreads();
    }
    offs[(size_t)t * NB + b] = ps[t] - v;   // exclusive
    if (t == 511) colsum[b] = ps[t];
}

// ---- pass B2: exclusive scan of bucket totals -> bucket bases ----
__global__ __launch_bounds__(512) void base_k(const int* __restrict__ colsum,
                                              int* __restrict__ bucketbase) {
    __shared__ int ps[512];
    int t = threadIdx.x;
    int v = (t < NB) ? colsum[t] : 0;
    ps[t] = v; __syncthreads();
    for (int off = 1; off < 512; off <<= 1) {
        int add = (t >= off) ? ps[t - off] : 0;
        __syncthreads();
        ps[t] += add;
        __syncthreads();
    }
    if (t < NB) bucketbase[t] = ps[t] - v;
}

// ---- pass C: local-sort scatter (LDS reorder -> coalesced global writeout) ----
__global__ __launch_bounds__(512) void binfill_k(const int* __restrict__ src,
                                                 const int* __restrict__ dst,
                                                 const int* __restrict__ blockhist,
                                                 const int* __restrict__ offs,
                                                 const int* __restrict__ bucketbase,
                                                 unsigned* __restrict__ recs, int E) {
    __shared__ int ps[512];
    __shared__ int ls[NB + 1];      // local exclusive bucket starts (+ total)
    __shared__ int ggap[NB];        // global base - local start
    __shared__ int lcur[NB];
    __shared__ unsigned lrec[CHUNK];
    int blk = blockIdx.x, t = threadIdx.x;

    // phase 1: local scan of this block's bucket counts
    int c = (t < NB) ? blockhist[(size_t)blk * NB + t] : 0;
    ps[t] = c; __syncthreads();
    for (int off = 1; off < 512; off <<= 1) {
        int add = (t >= off) ? ps[t - off] : 0;
        __syncthreads();
        ps[t] += add;
        __syncthreads();
    }
    if (t == 0) ls[0] = 0;
    if (t < NB) ls[t + 1] = ps[t];       // inclusive -> starts shifted by 1
    __syncthreads();
    if (t < NB) {
        int lst = ls[t];
        lcur[t] = lst;
        ggap[t] = bucketbase[t] + offs[(size_t)blk * NB + t] - lst;
    }
    __syncthreads();

    // phase 2: scatter chunk into LDS at locally-sorted positions
    int lo = blk * CHUNK, hi = lo + CHUNK; if (hi > E) hi = E;
    for (int i = lo + t; i < hi; i += 512) {
        int d = dst[i];
        int b = d >> 8;
        int lp = atomicAdd(&lcur[b], 1);
        lrec[lp] = (unsigned)src[i] | ((unsigned)(d & (BN - 1)) << SRC_BITS);
    }
    __syncthreads();

    // phase 3: linear writeout; bucket of j via binary search in ls
    int cl = hi - lo;
    for (int j = t; j < cl; j += 512) {
        int lo2 = 0, hi2 = NB;
        while (hi2 - lo2 > 1) {
            int mid = (lo2 + hi2) >> 1;
            if (ls[mid] <= j) lo2 = mid; else hi2 = mid;
        }
        recs[ggap[lo2] + j] = lrec[j];
    }
}

// ---- pass D: degree partials (SEG blocks per bucket) ----
__global__ __launch_bounds__(512) void deg_s_k(const unsigned* __restrict__ recs,
                                               const int* __restrict__ bucketbase,
                                               const int* __restrict__ colsum,
                                               int* __restrict__ dpart) {
    int blk = blockIdx.x;
    int b = blk >> 2, sg = blk & (SEG - 1);
    __shared__ int hh[BN];
    if (threadIdx.x < BN) hh[threadIdx.x] = 0;
    __syncthreads();
    int base = bucketbase[b], cnt = colsum[b];
    int lo = base + (int)((long long)cnt * sg / SEG);
    int hi = base + (int)((long long)cnt * (sg + 1) / SEG);
    for (int i = lo + threadIdx.x; i < hi; i += 512)
        atomicAdd(&hh[recs[i] >> SRC_BITS], 1);
    __syncthreads();
    if (threadIdx.x < BN)
        dpart[(size_t)sg * NPAD + b * BN + threadIdx.x] = hh[threadIdx.x];
}

__global__ __launch_bounds__(512) void deg_c_k(const float* __restrict__ x,
                                               const int* __restrict__ dpart,
                                               float* __restrict__ dinv,
                                               float* __restrict__ p, int N) {
    int n = blockIdx.x * blockDim.x + threadIdx.x;
    if (n < N) {
        int d = dpart[n] + dpart[NPAD + n] + dpart[2 * NPAD + n] + dpart[3 * NPAD + n];
        float di = rsqrtf((float)(d + 1));   // +1 self-loop
        dinv[n] = di;
        p[n] = x[n] * di;
    }
}

// ---- pass E: layer1 aggregate partials + combine (fused MLP -> g) ----
__global__ __launch_bounds__(512) void agg1_s_k(const unsigned* __restrict__ recs,
                                                const int* __restrict__ bucketbase,
                                                const int* __restrict__ colsum,
                                                const float* __restrict__ p,
                                                float* __restrict__ a1part) {
    int blk = blockIdx.x;
    int b = blk >> 2, sg = blk & (SEG - 1);
    __shared__ float acc[BN];
    if (threadIdx.x < BN) acc[threadIdx.x] = 0.f;
    __syncthreads();
    int base = bucketbase[b], cnt = colsum[b];
    int lo = base + (int)((long long)cnt * sg / SEG);
    int hi = base + (int)((long long)cnt * (sg + 1) / SEG);
    for (int i = lo + threadIdx.x; i < hi; i += 512) {
        unsigned r = recs[i];
        atomicAdd(&acc[r >> SRC_BITS], p[r & SRC_MASK]);
    }
    __syncthreads();
    if (threadIdx.x < BN)
        a1part[(size_t)sg * NPAD + b * BN + threadIdx.x] = acc[threadIdx.x];
}

__global__ __launch_bounds__(512) void agg1_c_k(const float* __restrict__ dinv,
                                                const float* __restrict__ p,
                                                const float* __restrict__ a1part,
                                                const float* __restrict__ W1,
                                                const float* __restrict__ b1,
                                                const float* __restrict__ W2,
                                                float2* __restrict__ g, int N) {
    int n = blockIdx.x * blockDim.x + threadIdx.x;
    if (n < N) {
        float sum = a1part[n] + a1part[NPAD + n] + a1part[2 * NPAD + n] + a1part[3 * NPAD + n];
        float di = dinv[n];
        float s = di * (p[n] + sum);
        float g0 = 0.f, g1 = 0.f;
        #pragma unroll
        for (int k = 0; k < 16; ++k) {
            float h = fmaxf(fmaf(W1[k], s, b1[k]), 0.f);
            g0 = fmaf(h, W2[2 * k + 0], g0);
            g1 = fmaf(h, W2[2 * k + 1], g1);
        }
        g[n] = make_float2(g0 * di, g1 * di);
    }
}

// ---- pass F: layer2 aggregate partials + combine (fused log_softmax -> out) ----
__global__ __launch_bounds__(512) void agg2_s_k(const unsigned* __restrict__ recs,
                                                const int* __restrict__ bucketbase,
                                                const int* __restrict__ colsum,
                                                const float2* __restrict__ g,
                                                float2* __restrict__ a2part) {
    int blk = blockIdx.x;
    int b = blk >> 2, sg = blk & (SEG - 1);
    __shared__ float a0[BN], a1[BN];
    if (threadIdx.x < BN) { a0[threadIdx.x] = 0.f; a1[threadIdx.x] = 0.f; }
    __syncthreads();
    int base = bucketbase[b], cnt = colsum[b];
    int lo = base + (int)((long long)cnt * sg / SEG);
    int hi = base + (int)((long long)cnt * (sg + 1) / SEG);
    for (int i = lo + threadIdx.x; i < hi; i += 512) {
        unsigned r = recs[i];
        float2 gv = g[r & SRC_MASK];
        int li = r >> SRC_BITS;
        atomicAdd(&a0[li], gv.x);
        atomicAdd(&a1[li], gv.y);
    }
    __syncthreads();
    if (threadIdx.x < BN)
        a2part[(size_t)sg * NPAD + b * BN + threadIdx.x] =
            make_float2(a0[threadIdx.x], a1[threadIdx.x]);
}

__global__ __launch_bounds__(512) void agg2_c_k(const float* __restrict__ dinv,
                                                const float2* __restrict__ g,
                                                const float2* __restrict__ a2part,
                                                const float* __restrict__ b2,
                                                float2* __restrict__ out, int N) {
    int n = blockIdx.x * blockDim.x + threadIdx.x;
    if (n < N) {
        float2 q0 = a2part[n], q1 = a2part[NPAD + n];
        float2 q2 = a2part[2 * NPAD + n], q3 = a2part[3 * NPAD + n];
        float s0 = q0.x + q1.x + q2.x + q3.x;
        float s1 = q0.y + q1.y + q2.y + q3.y;
        float di = dinv[n];
        float2 gv = g[n];
        float o0 = fmaf(di, gv.x + s0, b2[0]);
        float o1 = fmaf(di, gv.y + s1, b2[1]);
        float m = fmaxf(o0, o1);
        float lse = m + logf(expf(o0 - m) + expf(o1 - m));
        out[n] = make_float2(o0 - lse, o1 - lse);
    }
}

// ---------------- fallback atomic path (round-3 baseline) ----------------

__global__ void count_deg_k(const int* __restrict__ dst, int* __restrict__ degi, int E) {
    int i = blockIdx.x * blockDim.x + threadIdx.x;
    if (i < E) atomicAdd(&degi[dst[i]], 1);
}
__global__ void node1_k(const float* __restrict__ x, const int* __restrict__ degi,
                        float* __restrict__ dinv, float* __restrict__ p, int N) {
    int n = blockIdx.x * blockDim.x + threadIdx.x;
    if (n < N) {
        float di = rsqrtf((float)(degi[n] + 1));
        dinv[n] = di;
        p[n] = x[n] * di;
    }
}
__global__ void scatter1_k(const int* __restrict__ src, const int* __restrict__ dst,
                           const float* __restrict__ p, float* __restrict__ acc1, int E) {
    int i = blockIdx.x * blockDim.x + threadIdx.x;
    if (i < E) atomicAdd(&acc1[dst[i]], p[src[i]]);
}
__global__ void node2_k(const float* __restrict__ dinv, const float* __restrict__ p,
                        const float* __restrict__ acc1, const float* __restrict__ W1,
                        const float* __restrict__ b1, const float* __restrict__ W2,
                        float2* __restrict__ g, int N) {
    int n = blockIdx.x * blockDim.x + threadIdx.x;
    if (n < N) {
        float di = dinv[n];
        float s = di * (p[n] + acc1[n]);
        float g0 = 0.f, g1 = 0.f;
        #pragma unroll
        for (int k = 0; k < 16; ++k) {
            float h = fmaxf(fmaf(W1[k], s, b1[k]), 0.f);
            g0 = fmaf(h, W2[2 * k + 0], g0);
            g1 = fmaf(h, W2[2 * k + 1], g1);
        }
        g[n] = make_float2(g0 * di, g1 * di);
    }
}
__global__ void scatter2_k(const int* __restrict__ src, const int* __restrict__ dst,
                           const float2* __restrict__ g, float* __restrict__ acc2, int E) {
    int i = blockIdx.x * blockDim.x + threadIdx.x;
    if (i < E) {
        float2 gv = g[src[i]];
        int d = dst[i];
        atomicAdd(&acc2[2 * d + 0], gv.x);
        atomicAdd(&acc2[2 * d + 1], gv.y);
    }
}
__global__ void final_k(const float* __restrict__ dinv, const float2* __restrict__ g,
                        const float2* __restrict__ acc2, const float* __restrict__ b2,
                        float2* __restrict__ out, int N) {
    int n = blockIdx.x * blockDim.x + threadIdx.x;
    if (n < N) {
        float di = dinv[n];
        float2 gv = g[n];
        float2 av = acc2[n];
        float o0 = fmaf(di, gv.x + av.x, b2[0]);
        float o1 = fmaf(di, gv.y + av.y, b2[1]);
        float m = fmaxf(o0, o1);
        float lse = m + logf(expf(o0 - m) + expf(o1 - m));
        out[n] = make_float2(o0 - lse, o1 - lse);
    }
}

extern "C" void kernel_launch(void* const* d_in, const int* in_sizes, int n_in,
                              void* d_out, int out_size, void* d_ws, size_t ws_size,
                              hipStream_t stream) {
    const float* x  = (const float*)d_in[0];
    const int*   ei = (const int*)d_in[1];
    const float* W1 = (const float*)d_in[2];
    const float* b1 = (const float*)d_in[3];
    const float* W2 = (const float*)d_in[4];
    const float* b2 = (const float*)d_in[5];
    float2* out = (float2*)d_out;

    const int N = in_sizes[0];
    const int E = in_sizes[1] / 2;
    const int* src = ei;
    const int* dst = ei + E;

    // binned-path workspace layout
    size_t o_recs = 0;
    size_t o_bh   = o_recs + ((size_t)E * 4 + 255 & ~255UL);
    size_t o_offs = o_bh   + ((size_t)B1 * NB * 4 + 255 & ~255UL);
    size_t o_cs   = o_offs + ((size_t)B1 * NB * 4 + 255 & ~255UL);
    size_t o_bb   = o_cs   + ((size_t)NB * 4 + 255 & ~255UL);
    size_t o_dinv = o_bb   + ((size_t)NB * 4 + 255 & ~255UL);
    size_t o_p    = o_dinv + ((size_t)N * 4 + 255 & ~255UL);
    size_t o_g    = o_p    + ((size_t)N * 4 + 255 & ~255UL);
    size_t o_dp   = o_g    + ((size_t)N * 8 + 255 & ~255UL);
    size_t o_a1p  = o_dp   + ((size_t)SEG * NPAD * 4 + 255 & ~255UL);
    size_t o_a2p  = o_a1p  + ((size_t)SEG * NPAD * 4 + 255 & ~255UL);
    size_t need   = o_a2p  + (size_t)SEG * NPAD * 8;

    if (N == NNODES && E == NEDGES && ws_size >= need) {
        char* ws = (char*)d_ws;
        unsigned* recs = (unsigned*)(ws + o_recs);
        int* blockhist = (int*)(ws + o_bh);
        int* offs      = (int*)(ws + o_offs);
        int* colsum    = (int*)(ws + o_cs);
        int* bucketbase= (int*)(ws + o_bb);
        float* dinv    = (float*)(ws + o_dinv);
        float* p       = (float*)(ws + o_p);
        float2* g      = (float2*)(ws + o_g);
        int* dpart     = (int*)(ws + o_dp);
        float* a1part  = (float*)(ws + o_a1p);
        float2* a2part = (float2*)(ws + o_a2p);

        const int gN = (N + 511) / 512;
        hist_k   <<<B1, 512, 0, stream>>>(dst, blockhist, E);
        scanblk_k<<<NB, 512, 0, stream>>>(blockhist, offs, colsum);
        base_k   <<<1, 512, 0, stream>>>(colsum, bucketbase);
        binfill_k<<<B1, 512, 0, stream>>>(src, dst, blockhist, offs, bucketbase, recs, E);
        deg_s_k  <<<NB * SEG, 512, 0, stream>>>(recs, bucketbase, colsum, dpart);
        deg_c_k  <<<gN, 512, 0, stream>>>(x, dpart, dinv, p, N);
        agg1_s_k <<<NB * SEG, 512, 0, stream>>>(recs, bucketbase, colsum, p, a1part);
        agg1_c_k <<<gN, 512, 0, stream>>>(dinv, p, a1part, W1, b1, W2, g, N);
        agg2_s_k <<<NB * SEG, 512, 0, stream>>>(recs, bucketbase, colsum, g, a2part);
        agg2_c_k <<<gN, 512, 0, stream>>>(dinv, g, a2part, b2, out, N);
    } else {
        // fallback: round-3 atomic pipeline
        char* ws = (char*)d_ws;
        int*    degi = (int*)(ws);
        float*  acc1 = (float*)(ws + 4UL * N);
        float*  acc2 = (float*)(ws + 8UL * N);
        float*  dinvf= (float*)(ws + 16UL * N);
        float*  pf   = (float*)(ws + 20UL * N);
        float2* gf   = (float2*)(ws + 24UL * N);
        const int B = 256;
        const int gE = (E + B - 1) / B;
        const int gNf = (N + B - 1) / B;
        hipMemsetAsync(ws, 0, 16UL * N, stream);
        count_deg_k<<<gE, B, 0, stream>>>(dst, degi, E);
        node1_k<<<gNf, B, 0, stream>>>(x, degi, dinvf, pf, N);
        scatter1_k<<<gE, B, 0, stream>>>(src, dst, pf, acc1, E);
        node2_k<<<gNf, B, 0, stream>>>(dinvf, pf, acc1, W1, b1, W2, gf, N);
        scatter2_k<<<gE, B, 0, stream>>>(src, dst, gf, acc2, E);
        final_k<<<gNf, B, 0, stream>>>(dinvf, gf, (const float2*)acc2, b2, out, N);
    }
}